// Round 1
// 183.761 us; speedup vs baseline: 1.0431x; 1.0431x over previous
//
#include <hip/hip_runtime.h>
#include <hip/hip_bf16.h>
#include <math.h>

#define NTOT 2048   // N*T
#define DIM  128    // D == E1
#define MSPLIT 8    // split-K for gk_mlp1t
#define ZSPLIT 8    // split-K for xz_k
#define JT 16       // jsd tile width (columns)
#define JNC 128     // jsd n-chunk in LDS
#define JNSPLIT 8   // jsd n splits

struct P4 { const float* p[4]; };

// ---------------------------------------------------------------- H pipeline
// Gs[k][split] = partial X_k^T @ W1_k  (no atomics; consumer sums splits)
// grid (16 tiles, MSPLIT, 4 k), block 256. Register double-buffered staging:
// next tile's global loads issue before the inner product so HBM/L2 latency
// hides under the 32-step FMA block.
__global__ __launch_bounds__(256) void gk_mlp1t(P4 X, P4 W1, float* __restrict__ Gs) {
  int k = blockIdx.z;
  int m0 = (blockIdx.x & 3) * 32;
  int e0 = (blockIdx.x >> 2) * 32;
  int split = blockIdx.y;
  int n0 = split * (NTOT / MSPLIT);
  const float* Xp = X.p[k];
  const float* Wp = W1.p[k];
  __shared__ float Xs[32][36], Ws[32][36];   // 36: row-aligned for b128 stores
  int tid = threadIdx.x;
  int lr = tid >> 3;              // load row 0..31
  int lc = (tid & 7) * 4;         // load col 0,4,..28
  int tx = tid & 15, ty = tid >> 4;
  float a00 = 0.f, a01 = 0.f, a10 = 0.f, a11 = 0.f;
  long g0 = (long)(n0 + lr) * DIM;
  float4 xv = *(const float4*)(Xp + g0 + m0 + lc);   // prefetch tile 0
  float4 wv = *(const float4*)(Wp + g0 + e0 + lc);
  for (int nb = 0; nb < NTOT / MSPLIT; nb += 32) {
    *(float4*)&Xs[lr][lc] = xv;
    *(float4*)&Ws[lr][lc] = wv;
    __syncthreads();
    if (nb + 32 < NTOT / MSPLIT) {                   // prefetch tile nb+32
      long gn = (long)(n0 + nb + 32 + lr) * DIM;
      xv = *(const float4*)(Xp + gn + m0 + lc);
      wv = *(const float4*)(Wp + gn + e0 + lc);
    }
    #pragma unroll
    for (int nn = 0; nn < 32; ++nn) {
      float x0 = Xs[nn][2*ty], x1 = Xs[nn][2*ty+1];
      float w0 = Ws[nn][2*tx], w1 = Ws[nn][2*tx+1];
      a00 += x0 * w0; a01 += x0 * w1;
      a10 += x1 * w0; a11 += x1 * w1;
    }
    __syncthreads();
  }
  float* Gk = Gs + ((long)k * MSPLIT + split) * 16384;
  int m = m0 + 2 * ty, e = e0 + 2 * tx;
  Gk[m * DIM + e]           = a00;
  Gk[m * DIM + e + 1]       = a01;
  Gk[(m + 1) * DIM + e]     = a10;
  Gk[(m + 1) * DIM + e + 1] = a11;
}

// Fused gk_mlp2 + gk_ab (one launch, no Mk round-trip).
// Per block m: M_k[m,e] for all 4 k (LDS), then
//   A[m,e] = sum_j M_it[m,j]*fW1[j,e]      + M_t2n[m,j]*fW1[256+j,e]
//   B[m,e] = sum_j M_inw[m,j]*fW1[128+j,e] + M_n2t[m,j]*fW1[384+j,e]
// 256 threads: half = tid>>7 owns k-pair {half, half+2} then output row half
// (A or B). Dual accumulators keep 2 load streams in flight (latency-bound).
// grid 128, block 256
__global__ __launch_bounds__(256) void gk_mab(const float* __restrict__ Gs, P4 B1, P4 W2, P4 B2,
                                              const float* __restrict__ fW1, float* __restrict__ AB) {
  int m = blockIdx.x;
  int e = threadIdx.x & 127;
  int half = threadIdx.x >> 7;      // 0,1
  int k0 = half, k1 = half + 2;
  __shared__ float rk[4][DIM];      // relu(sum_s Gs + b1)
  __shared__ float mk[4][DIM];      // M rows
  {
    const float* G0 = Gs + (long)k0 * MSPLIT * 16384 + m * DIM + e;
    const float* G1 = Gs + (long)k1 * MSPLIT * 16384 + m * DIM + e;
    float s0 = 0.f, s1 = 0.f;
    #pragma unroll
    for (int s = 0; s < MSPLIT; ++s) { s0 += G0[s * 16384]; s1 += G1[s * 16384]; }
    rk[k0][e] = fmaxf(s0 + B1.p[k0][e], 0.f);
    rk[k1][e] = fmaxf(s1 + B1.p[k1][e], 0.f);
  }
  __syncthreads();
  {
    const float* Wa = W2.p[k0];
    const float* Wb = W2.p[k1];
    float a0 = B2.p[k0][e], a1 = B2.p[k1][e];
    #pragma unroll 8
    for (int j = 0; j < DIM; ++j) {
      a0 += rk[k0][j] * Wa[j * DIM + e];
      a1 += rk[k1][j] * Wb[j * DIM + e];
    }
    mk[k0][e] = a0;
    mk[k1][e] = a1;
  }
  __syncthreads();
  const float* Ma = mk[half];           // h=0: it ; h=1: inw
  const float* Mb = mk[half + 2];       // h=0: t2n; h=1: n2t
  const float* W0 = fW1 + (half == 0 ? 0 : 128) * DIM;
  const float* W1p = fW1 + (half == 0 ? 256 : 384) * DIM;
  float acc = 0.f;
  #pragma unroll 8
  for (int j = 0; j < DIM; ++j)
    acc += Ma[j] * W0[j * DIM + e] + Mb[j] * W1p[j * DIM + e];
  AB[(long)half * 16384 + m * DIM + e] = acc;
}

// Fused H1+H2, 8 rows per block (256 blocks = 1/CU), transposed output.
// HrawT[e][n] = fb2[e] + sum_j relu( sum_k xt[n,k]A[k,e]+xn[n,k]B[k,e] + fb1[j->e] ) fW2[j,e]
// x tiles stored transposed [k][r] so a wave's 4-row fragment is ONE
// wave-uniform ds_read_b128 (broadcast, conflict-free). Weight streams
// (AB, fW2) read once per 8 rows: L2 traffic 384MB -> 64MB vs old gk_h12.
// Output written as HrawT (one float4/thread) so colsoft reads coalesce.
__global__ __launch_bounds__(256) void gk_h12t(const float* __restrict__ xt, const float* __restrict__ xn,
                                               const float* __restrict__ AB, const float* __restrict__ fb1,
                                               const float* __restrict__ fW2, const float* __restrict__ fb2,
                                               float* __restrict__ HrawT) {
  int n0 = blockIdx.x * 8;                 // 256 blocks
  int e  = threadIdx.x & 127;
  int rr = (threadIdx.x >> 7) << 2;        // 0 or 4 (wave-uniform)
  __shared__ float stT[DIM][8], snT[DIM][8], h1T[DIM][8];
  {
    // stage x transposed: thread (c=tid&31, rq=tid>>5) loads 4 strided dwords
    // (coalesced across c); LDS writes are 8-way conflicted but one-time.
    int c = threadIdx.x & 31, rq = threadIdx.x >> 5;
    const float* xtr = xt + (long)(n0 + rq) * DIM;
    const float* xnr = xn + (long)(n0 + rq) * DIM;
    #pragma unroll
    for (int i = 0; i < 4; ++i) {
      int d = c + 32 * i;
      stT[d][rq] = xtr[d];
      snT[d][rq] = xnr[d];
    }
  }
  __syncthreads();
  float4 acc1 = make_float4(0.f, 0.f, 0.f, 0.f);   // rows n0+rr..+3, col e
  #pragma unroll 8
  for (int k = 0; k < DIM; ++k) {
    float a = AB[k * DIM + e];
    float b = AB[16384 + k * DIM + e];
    const float4 xv = *(const float4*)&stT[k][rr];  // broadcast b128
    const float4 nv = *(const float4*)&snT[k][rr];
    acc1.x += xv.x * a + nv.x * b;
    acc1.y += xv.y * a + nv.y * b;
    acc1.z += xv.z * a + nv.z * b;
    acc1.w += xv.w * a + nv.w * b;
  }
  float b1v = fb1[e];
  float4 h1;
  h1.x = fmaxf(acc1.x + b1v, 0.f);
  h1.y = fmaxf(acc1.y + b1v, 0.f);
  h1.z = fmaxf(acc1.z + b1v, 0.f);
  h1.w = fmaxf(acc1.w + b1v, 0.f);
  *(float4*)&h1T[e][rr] = h1;
  __syncthreads();
  float4 acc2 = make_float4(0.f, 0.f, 0.f, 0.f);
  #pragma unroll 8
  for (int j = 0; j < DIM; ++j) {
    float wv = fW2[j * DIM + e];
    const float4 hv = *(const float4*)&h1T[j][rr];  // broadcast b128
    acc2.x += hv.x * wv;
    acc2.y += hv.y * wv;
    acc2.z += hv.z * wv;
    acc2.w += hv.w * wv;
  }
  float b2v = fb2[e];
  float4 o;
  o.x = acc2.x + b2v; o.y = acc2.y + b2v; o.z = acc2.z + b2v; o.w = acc2.w + b2v;
  *(float4*)&HrawT[(long)e * NTOT + n0 + rr] = o;   // transposed, contiguous
}

// ---------------------------------------------------------------- reductions
// fused colstats+softmax (one block/column, column register-resident).
// Hraw now arrives TRANSPOSED -> reads are fully coalesced along n.
// Block 0 also zeroes Gacc (jsd runs strictly after this kernel).
__global__ __launch_bounds__(256) void colsoft_k(const float* __restrict__ HrawT,
                                                 float* __restrict__ HTp, float* __restrict__ Ecol,
                                                 float* __restrict__ Gacc) {
  int e = blockIdx.x;
  int t = threadIdx.x;
  if (e == 0 && t < DIM) Gacc[t] = 0.f;
  __shared__ float sa[4], sb[4], sc[4];
  float v[8];
  float sum = 0.f, sq = 0.f, mx = -3.4e38f;
  #pragma unroll
  for (int r = 0; r < 8; ++r) {
    float x = HrawT[(long)e * NTOT + t + 256 * r];   // coalesced
    v[r] = x;
    sum += x; sq += x * x; mx = fmaxf(mx, x);
  }
  #pragma unroll
  for (int o = 32; o > 0; o >>= 1) {
    sum += __shfl_down(sum, o);
    sq  += __shfl_down(sq, o);
    mx   = fmaxf(mx, __shfl_down(mx, o));
  }
  if ((t & 63) == 0) { int w = t >> 6; sa[w] = sum; sb[w] = sq; sc[w] = mx; }
  __syncthreads();
  sum = sa[0] + sa[1] + sa[2] + sa[3];
  sq  = sb[0] + sb[1] + sb[2] + sb[3];
  mx  = fmaxf(fmaxf(sc[0], sc[1]), fmaxf(sc[2], sc[3]));
  float mean = sum * (1.f / NTOT);
  float var  = (sq - sum * mean) * (1.f / (NTOT - 1));
  float ia   = 1.f / (sqrtf(fmaxf(var, 0.f)) + 1e-6f);
  float smax = (mx - mean) * ia;
  __syncthreads();

  float den = 0.f;
  #pragma unroll
  for (int r = 0; r < 8; ++r) {
    float s = (v[r] - mean) * ia - smax;
    v[r] = s;
    den += __expf(s);
  }
  #pragma unroll
  for (int o = 32; o > 0; o >>= 1) den += __shfl_down(den, o);
  if ((t & 63) == 0) sa[t >> 6] = den;
  __syncthreads();
  den = sa[0] + sa[1] + sa[2] + sa[3];
  float logden = __logf(den);
  float invden = 1.f / den;
  __syncthreads();

  float ent = 0.f;
  #pragma unroll
  for (int r = 0; r < 8; ++r) {
    float s = v[r];
    float pv = __expf(s) * invden;
    HTp[(long)e * NTOT + t + 256 * r] = pv;
    ent += pv * (s - logden);
  }
  #pragma unroll
  for (int o = 32; o > 0; o >>= 1) ent += __shfl_down(ent, o);
  if ((t & 63) == 0) sa[t >> 6] = ent;
  __syncthreads();
  if (t == 0) Ecol[e] = sa[0] + sa[1] + sa[2] + sa[3];
}

// tiled pairwise-JSD log part: g[i] -= sum_{j!=i} sum_n (a+b)*log((a+b)/2)
__global__ __launch_bounds__(256) void jsd_tile(const float* __restrict__ HTp,
                                                float* __restrict__ g) {
  int b = blockIdx.x;
  int bi = 0, rem = b;
  while (rem >= 8 - bi) { rem -= 8 - bi; ++bi; }
  int bj = bi + rem;                      // bi <= bj
  int n0 = blockIdx.y * (NTOT / JNSPLIT);

  __shared__ float Ti[JT][JNC + 2];
  __shared__ float Tj[JT][JNC + 2];
  __shared__ float red[JT][JT + 1];

  int tid = threadIdx.x;
  int ti = tid >> 4, tj = tid & 15;
  bool active = (bi != bj) || (ti < tj);
  float acc = 0.f;

  int lc = tid >> 4;
  int ln = (tid & 15) * 8;

  for (int c = 0; c < NTOT / JNSPLIT; c += JNC) {
    const float* si = HTp + (long)(bi * JT + lc) * NTOT + n0 + c + ln;
    const float* sj = HTp + (long)(bj * JT + lc) * NTOT + n0 + c + ln;
    #pragma unroll
    for (int r = 0; r < 8; ++r) Ti[lc][ln + r] = si[r];
    #pragma unroll
    for (int r = 0; r < 8; ++r) Tj[lc][ln + r] = sj[r];
    __syncthreads();
    if (active) {
      #pragma unroll 4
      for (int n = 0; n < JNC; ++n) {
        float s = Ti[ti][n] + Tj[tj][n];
        acc += s * __logf(fmaxf(0.5f * s, 1e-38f));
      }
    }
    __syncthreads();
  }

  red[ti][tj] = active ? acc : 0.f;
  __syncthreads();
  if (tid < JT) {
    float s = 0.f;
    #pragma unroll
    for (int j = 0; j < JT; ++j) s += red[tid][j];
    atomicAdd(&g[bi * JT + tid], -s);
  } else if (tid < 2 * JT) {
    int c2 = tid - JT;
    float s = 0.f;
    #pragma unroll
    for (int i = 0; i < JT; ++i) s += red[i][c2];
    atomicAdd(&g[bj * JT + c2], -s);
  }
}

// ---------------------------------------------------------------- final chain
// Xzs[bt][split][e][d] = partial sum_n Hsoft[n,e] x[n][d]  (no atomics)
// grid (16, ZSPLIT, 2), block 256. Register double-buffered staging.
__global__ __launch_bounds__(256) void xz_k(const float* __restrict__ HTp, const float* __restrict__ xt,
                                            const float* __restrict__ xn, float* __restrict__ Xzs) {
  int bt = blockIdx.z;
  const float* x = bt ? xn : xt;
  int split = blockIdx.y;
  float* C = Xzs + ((long)bt * ZSPLIT + split) * 16384;
  int e0 = (blockIdx.x & 3) * 32, d0 = (blockIdx.x >> 2) * 32;
  int n0 = split * (NTOT / ZSPLIT);
  __shared__ float As[32][33], Bs[32][36];   // As[n][e], Bs[n][d]
  int tid = threadIdx.x, col = tid & 31, row = tid >> 5;
  int lr = tid >> 3, lc4 = (tid & 7) * 4;
  int tx = tid & 15, ty = tid >> 4;
  float a00 = 0.f, a01 = 0.f, a10 = 0.f, a11 = 0.f;
  float pa[4]; float4 pb;
  #pragma unroll
  for (int r = 0; r < 4; ++r) pa[r] = HTp[(long)(e0 + row + r * 8) * NTOT + n0 + col];
  pb = *(const float4*)(x + (long)(n0 + lr) * DIM + d0 + lc4);
  for (int nb = 0; nb < NTOT / ZSPLIT; nb += 32) {
    #pragma unroll
    for (int r = 0; r < 4; ++r) As[col][row + r * 8] = pa[r];
    *(float4*)&Bs[lr][lc4] = pb;
    __syncthreads();
    if (nb + 32 < NTOT / ZSPLIT) {
      #pragma unroll
      for (int r = 0; r < 4; ++r)
        pa[r] = HTp[(long)(e0 + row + r * 8) * NTOT + n0 + nb + 32 + col];
      pb = *(const float4*)(x + (long)(n0 + nb + 32 + lr) * DIM + d0 + lc4);
    }
    #pragma unroll
    for (int nn = 0; nn < 32; ++nn) {
      float e0v = As[nn][2*ty], e1v = As[nn][2*ty+1];
      float d0v = Bs[nn][2*tx], d1v = Bs[nn][2*tx+1];
      a00 += e0v * d0v; a01 += e0v * d1v;
      a10 += e1v * d0v; a11 += e1v * d1v;
    }
    __syncthreads();
  }
  int e = e0 + 2 * ty, d = d0 + 2 * tx;
  C[e * DIM + d]           = a00;
  C[e * DIM + d + 1]       = a01;
  C[(e + 1) * DIM + d]     = a10;
  C[(e + 1) * DIM + d + 1] = a11;
}

// Zw[bt][e][d] = w[e] * sum_k (sum_s Xzs[bt][s][e][k]) * theta[k][d]
// w (formerly wvec_k) is inlined: every block redundantly recomputes the
// 128-wide standardize+softmax reduction (~0.5us, parallel) and keeps w[e].
// Saves one serial launch. grid (128, 2), block 128.
__global__ __launch_bounds__(128) void zs_k(const float* __restrict__ Xzs, const float* __restrict__ thT,
                                            const float* __restrict__ thN, const float* __restrict__ g,
                                            const float* __restrict__ Ecol, float* __restrict__ Zw) {
  int e = blockIdx.x, d = threadIdx.x, bt = blockIdx.y;
  __shared__ float s2[2];
  __shared__ float swv;
  int t = d;
  float ec = Ecol[t];
  float v = ec;
  #pragma unroll
  for (int o = 32; o > 0; o >>= 1) v += __shfl_down(v, o);
  if ((t & 63) == 0) s2[t >> 6] = v;
  __syncthreads();
  float S = s2[0] + s2[1];
  __syncthreads();
  float jm = (g[t] + 126.f * ec + S) * (1.0f / 256.0f);
  v = jm;
  #pragma unroll
  for (int o = 32; o > 0; o >>= 1) v += __shfl_down(v, o);
  if ((t & 63) == 0) s2[t >> 6] = v;
  __syncthreads();
  float mean = (s2[0] + s2[1]) * (1.0f / 128.0f);
  __syncthreads();
  float dv = jm - mean;
  v = dv * dv;
  #pragma unroll
  for (int o = 32; o > 0; o >>= 1) v += __shfl_down(v, o);
  if ((t & 63) == 0) s2[t >> 6] = v;
  __syncthreads();
  float var = (s2[0] + s2[1]) * (1.0f / 127.0f);
  float njm = dv / (sqrtf(var) + 1e-6f);
  __syncthreads();
  v = njm;
  #pragma unroll
  for (int o = 32; o > 0; o >>= 1) v = fmaxf(v, __shfl_down(v, o));
  if ((t & 63) == 0) s2[t >> 6] = v;
  __syncthreads();
  float mx = fmaxf(s2[0], s2[1]);
  float ex = __expf(njm - mx);
  __syncthreads();
  v = ex;
  #pragma unroll
  for (int o = 32; o > 0; o >>= 1) v += __shfl_down(v, o);
  if ((t & 63) == 0) s2[t >> 6] = v;
  __syncthreads();
  if (t == e) swv = ex / (s2[0] + s2[1]);
  __syncthreads();
  float we = swv;

  const float* src = Xzs + (long)bt * ZSPLIT * 16384 + e * DIM + d;
  const float* th = bt ? thN : thT;
  __shared__ float s[DIM];
  float xv = 0.f;
  #pragma unroll
  for (int sp = 0; sp < ZSPLIT; ++sp) xv += src[sp * 16384];
  s[d] = xv;
  __syncthreads();
  float acc = 0.f;
  #pragma unroll 8
  for (int k = 0; k < DIM; ++k) acc += s[k] * th[(long)k * DIM + d];
  Zw[bt * 16384 + e * DIM + d] = acc * we;
}

// out[n][d] = x[n][d] + elu( sum_e Hsoft[n,e] Zw[e][d] )  (H read from HTp)
// grid (4, 64, 2), block 256. Register double-buffered staging.
__global__ __launch_bounds__(256) void uk_t(const float* __restrict__ HTp, const float* __restrict__ Zw,
                                            const float* __restrict__ xt, const float* __restrict__ xn,
                                            float* __restrict__ out) {
  int bt = blockIdx.z;
  const float* x = bt ? xn : xt;
  const float* B = Zw + bt * 16384;
  float* o = out + (long)bt * NTOT * DIM;
  int d0 = blockIdx.x * 32, n0 = blockIdx.y * 32;
  __shared__ float As[32][33], Bs[32][36];   // As[n][e], Bs[e][d]
  int tid = threadIdx.x, col = tid & 31, row = tid >> 5;
  int lr = tid >> 3, lc4 = (tid & 7) * 4;
  int tx = tid & 15, ty = tid >> 4;
  float a00 = 0.f, a01 = 0.f, a10 = 0.f, a11 = 0.f;
  float pa[4]; float4 pb;
  #pragma unroll
  for (int r = 0; r < 4; ++r) pa[r] = HTp[(long)(row + r * 8) * NTOT + n0 + col];
  pb = *(const float4*)(B + (long)lr * DIM + d0 + lc4);
  for (int eb = 0; eb < DIM; eb += 32) {
    #pragma unroll
    for (int r = 0; r < 4; ++r) As[col][row + r * 8] = pa[r];
    *(float4*)&Bs[lr][lc4] = pb;
    __syncthreads();
    if (eb + 32 < DIM) {
      #pragma unroll
      for (int r = 0; r < 4; ++r)
        pa[r] = HTp[(long)(eb + 32 + row + r * 8) * NTOT + n0 + col];
      pb = *(const float4*)(B + (long)(eb + 32 + lr) * DIM + d0 + lc4);
    }
    #pragma unroll
    for (int ee = 0; ee < 32; ++ee) {
      float x0 = As[2*ty][ee], x1 = As[2*ty+1][ee];
      float b0 = Bs[ee][2*tx], b1 = Bs[ee][2*tx+1];
      a00 += x0 * b0; a01 += x0 * b1;
      a10 += x1 * b0; a11 += x1 * b1;
    }
    __syncthreads();
  }
  int n = n0 + 2 * ty, d = d0 + 2 * tx;
  long i0 = (long)n * DIM + d, i1 = i0 + DIM;
  float e00 = a00 > 0.f ? a00 : expm1f(a00);
  float e01 = a01 > 0.f ? a01 : expm1f(a01);
  float e10 = a10 > 0.f ? a10 : expm1f(a10);
  float e11 = a11 > 0.f ? a11 : expm1f(a11);
  o[i0]     = x[i0]     + e00;
  o[i0 + 1] = x[i0 + 1] + e01;
  o[i1]     = x[i1]     + e10;
  o[i1 + 1] = x[i1 + 1] + e11;
}

// ---------------------------------------------------------------- launcher
extern "C" void kernel_launch(void* const* d_in, const int* in_sizes, int n_in,
                              void* d_out, int out_size, void* d_ws, size_t ws_size,
                              hipStream_t stream) {
  const float* xt = (const float*)d_in[0];   // x_time (f32 — proven rounds 1/2/10)
  const float* xn = (const float*)d_in[1];   // x_news
  const float *W1[4], *b1[4], *W2[4], *b2[4];
  for (int k = 0; k < 4; ++k) {           // it, inw, t2n, n2t
    W1[k] = (const float*)d_in[2 + 4*k];
    b1[k] = (const float*)d_in[3 + 4*k];
    W2[k] = (const float*)d_in[4 + 4*k];
    b2[k] = (const float*)d_in[5 + 4*k];
  }
  const float* fW1 = (const float*)d_in[18];
  const float* fb1 = (const float*)d_in[19];
  const float* fW2 = (const float*)d_in[20];
  const float* fb2 = (const float*)d_in[21];
  const float* thT = (const float*)d_in[22];
  const float* thN = (const float*)d_in[23];

  // ws map (floats), peak 1442176 = 5.77 MB (no zeroing needed anywhere)
  float* ws    = (float*)d_ws;
  float* Gacc  = ws;                  // [0,128)       zeroed by colsoft block 0
  float* Ecol  = ws + 128;            // [128,256)
  // ws + 256 .. 384: free (former Wv — w now computed inline in zs_k)
  float* Zw    = ws + 384;            // [384,33152)    (2 batch)
  float* Xzs   = ws + 33152;          // [33152,295296)  2*ZSPLIT*16384 split slabs
  float* Gs    = ws + 295296;         // [295296,819584) 4*MSPLIT*16384 split slabs
  // ws + 819584 .. 917888: free (former Mk — fused into gk_mab LDS)
  float* AB    = ws + 885120;         // [885120,917888)
  float* HrawT = ws + 917888;         // [917888,1180032)  (TRANSPOSED [e][n])
  float* HTp   = ws + 1180032;        // [1180032,1442176)

  float* out = (float*)d_out;         // f32 output, [time | news]

  P4 Xs  = {{xt, xn, xn, xt}};
  P4 W1s = {{W1[0], W1[1], W1[2], W1[3]}};
  P4 B1s = {{b1[0], b1[1], b1[2], b1[3]}};
  P4 W2s = {{W2[0], W2[1], W2[2], W2[3]}};
  P4 B2s = {{b2[0], b2[1], b2[2], b2[3]}};

  gk_mlp1t<<<dim3(16, MSPLIT, 4), 256, 0, stream>>>(Xs, W1s, Gs);
  gk_mab  <<<128, 256, 0, stream>>>(Gs, B1s, W2s, B2s, fW1, AB);
  gk_h12t <<<256, 256, 0, stream>>>(xt, xn, AB, fb1, fW2, fb2, HrawT);

  colsoft_k<<<DIM, 256, 0, stream>>>(HrawT, HTp, Ecol, Gacc);

  jsd_tile<<<dim3(36, JNSPLIT), 256, 0, stream>>>(HTp, Gacc);

  // z = (H^T x) theta (reassociated), scaled by inlined w; out = x + elu(H @ Zw)
  xz_k<<<dim3(16, ZSPLIT, 2), 256, 0, stream>>>(HTp, xt, xn, Xzs);
  zs_k<<<dim3(128, 2), 128, 0, stream>>>(Xzs, thT, thN, Gacc, Ecol, Zw);
  uk_t<<<dim3(4, 64, 2), 256, 0, stream>>>(HTp, Zw, xt, xn, out);

  (void)in_sizes; (void)n_in; (void)out_size; (void)ws_size;
}